// Round 1
// baseline (540.657 us; speedup 1.0000x reference)
//
#include <hip/hip_runtime.h>
#include <math.h>

#define NN 50000
#define EE 800000
#define INDIM 256
#define DD 32
#define HH 8
#define CC 256   // H*D
#define NEG 0.01f

// ---------- index dtype probe + normalize ----------
// If indices are int64 (little-endian, values < 50000), every high 32-bit word
// is zero. If int32, odd-position words are random node ids (P(all zero)~0).
// Only touch the first EE/2 "int64 slots" = first EE int32 words: bounds-safe
// for both layouts.
__global__ void k_detect(const unsigned* __restrict__ s, const unsigned* __restrict__ d,
                         int* __restrict__ flag) {
  unsigned v = 0;
  int stride = gridDim.x * blockDim.x;
  for (int e = blockIdx.x * blockDim.x + threadIdx.x; e < EE / 2; e += stride)
    v |= s[2 * e + 1] | d[2 * e + 1];
  if (v) atomicOr(flag, 1);   // 1 => indices are int32
}

__global__ void k_convert(const void* __restrict__ sraw, const void* __restrict__ draw,
                          const int* __restrict__ flag,
                          int* __restrict__ s32, int* __restrict__ d32) {
  const int is32 = *flag;
  int stride = gridDim.x * blockDim.x;
  for (int e = blockIdx.x * blockDim.x + threadIdx.x; e < EE; e += stride) {
    if (is32) {
      s32[e] = ((const int*)sraw)[e];
      d32[e] = ((const int*)draw)[e];
    } else {
      s32[e] = (int)((const long long*)sraw)[e];
      d32[e] = (int)((const long long*)draw)[e];
    }
  }
}

// ---------- z = h @ W  (+ el/er epilogue) ----------
// Block: 256 threads, 16 rows. Thread t owns output column c=t (head=t>>5, d=t&31)
// for 16 rows. A-tile staged in LDS; W streamed from L2 (256 KB, cache-resident).
__global__ __launch_bounds__(256) void k_gemm(const float* __restrict__ h,
                                              const float* __restrict__ W,
                                              const float* __restrict__ attn_w,
                                              float* __restrict__ z,
                                              float* __restrict__ el,
                                              float* __restrict__ er) {
  __shared__ float sA[16][INDIM];   // 16 KB
  const int t = threadIdx.x;
  const int row0 = blockIdx.x * 16;
  for (int r = 0; r < 16; ++r)
    sA[r][t] = h[(size_t)(row0 + r) * INDIM + t];
  __syncthreads();

  const int head = t >> 5, d = t & 31;
  const float al = attn_w[head * (2 * DD) + d];
  const float ar = attn_w[head * (2 * DD) + DD + d];
  const float* __restrict__ Bp = W + (size_t)head * INDIM * DD + d;

  float acc[16];
#pragma unroll
  for (int r = 0; r < 16; ++r) acc[r] = 0.f;

  for (int i0 = 0; i0 < INDIM; i0 += 4) {
    const float b0 = Bp[(i0 + 0) * DD];
    const float b1 = Bp[(i0 + 1) * DD];
    const float b2 = Bp[(i0 + 2) * DD];
    const float b3 = Bp[(i0 + 3) * DD];
#pragma unroll
    for (int r = 0; r < 16; ++r) {
      float4 a = *reinterpret_cast<const float4*>(&sA[r][i0]);
      acc[r] += a.x * b0 + a.y * b1 + a.z * b2 + a.w * b3;
    }
  }

#pragma unroll
  for (int r = 0; r < 16; ++r)
    z[(size_t)(row0 + r) * CC + t] = acc[r];

  // el/er: reduce over d (32 lanes within each half-wave)
  for (int r = 0; r < 16; ++r) {
    float vl = acc[r] * al;
    float vr = acc[r] * ar;
#pragma unroll
    for (int s = 1; s < 32; s <<= 1) {
      vl += __shfl_xor(vl, s);
      vr += __shfl_xor(vr, s);
    }
    if (d == 0) {
      el[(size_t)(row0 + r) * HH + head] = vl;
      er[(size_t)(row0 + r) * HH + head] = vr;
    }
  }
}

// ---------- CSR build ----------
__global__ void k_hist(const int* __restrict__ d32, int* __restrict__ counts) {
  int stride = gridDim.x * blockDim.x;
  for (int e = blockIdx.x * blockDim.x + threadIdx.x; e < EE; e += stride)
    atomicAdd(&counts[d32[e]], 1);
}

__global__ __launch_bounds__(1024) void k_scan1(const int* __restrict__ counts,
                                                int* __restrict__ row_start,
                                                int* __restrict__ partial) {
  __shared__ int s[1024];
  const int tid = threadIdx.x;
  const int i = blockIdx.x * 1024 + tid;
  int v = (i < NN) ? counts[i] : 0;
  s[tid] = v;
  __syncthreads();
  for (int off = 1; off < 1024; off <<= 1) {
    int tv = (tid >= off) ? s[tid - off] : 0;
    __syncthreads();
    s[tid] += tv;
    __syncthreads();
  }
  if (i < NN) row_start[i] = s[tid] - v;           // exclusive
  if (tid == 1023) partial[blockIdx.x] = s[1023];  // block total
}

__global__ void k_scan2(int* __restrict__ partial, int nb) {
  if (threadIdx.x == 0 && blockIdx.x == 0) {
    int acc = 0;
    for (int i = 0; i < nb; ++i) { int t = partial[i]; partial[i] = acc; acc += t; }
  }
}

__global__ void k_scan3(int* __restrict__ row_start, const int* __restrict__ partial) {
  int i = blockIdx.x * blockDim.x + threadIdx.x;
  if (i < NN) row_start[i] += partial[i >> 10];
}

__global__ void k_scatter(const int* __restrict__ s32, const int* __restrict__ d32,
                          const int* __restrict__ row_start, int* __restrict__ cursor,
                          int* __restrict__ csr_src) {
  int stride = gridDim.x * blockDim.x;
  for (int e = blockIdx.x * blockDim.x + threadIdx.x; e < EE; e += stride) {
    int dn = d32[e];
    int pos = row_start[dn] + atomicAdd(&cursor[dn], 1);
    csr_src[pos] = s32[e];
  }
}

// ---------- per-node softmax-aggregate ----------
// Block = 256 threads = one node. Thread t owns (head=t>>5, d=t&31).
// Pass 1: segment max (threads with same head compute redundantly; el load
// broadcasts). Pass 2: fused exp, den accumulation, weighted z gather-accumulate.
__global__ __launch_bounds__(256) void k_agg(const float* __restrict__ z,
                                             const float* __restrict__ el,
                                             const float* __restrict__ er,
                                             const int* __restrict__ row_start,
                                             const int* __restrict__ csr_src,
                                             float* __restrict__ out) {
  const int n = blockIdx.x;
  const int t = threadIdx.x;
  const int head = t >> 5;
  const int beg = row_start[n];
  const int end = (n == NN - 1) ? EE : row_start[n + 1];
  const float ern = er[(size_t)n * HH + head];

  float m = -INFINITY;
  for (int p = beg; p < end; ++p) {
    int s = csr_src[p];
    float v = el[(size_t)s * HH + head] + ern;
    v = (v > 0.f) ? v : v * NEG;
    m = fmaxf(m, v);
  }

  float den = 0.f, acc = 0.f;
  for (int p = beg; p < end; ++p) {
    int s = csr_src[p];
    float v = el[(size_t)s * HH + head] + ern;
    v = (v > 0.f) ? v : v * NEG;
    float w = __expf(v - m);
    den += w;
    acc += w * z[(size_t)s * CC + t];
  }
  out[(size_t)n * CC + t] = (den > 0.f) ? (acc / den) : 0.f;
}

extern "C" void kernel_launch(void* const* d_in, const int* in_sizes, int n_in,
                              void* d_out, int out_size, void* d_ws, size_t ws_size,
                              hipStream_t stream) {
  const float* h      = (const float*)d_in[0];
  const float* W      = (const float*)d_in[1];
  const float* attn_w = (const float*)d_in[2];
  const void*  src_raw = d_in[3];
  const void*  dst_raw = d_in[4];
  float* out = (float*)d_out;

  char* ws = (char*)d_ws;
  size_t off = 0;
  float* z  = (float*)(ws + off); off += (size_t)NN * CC * 4;   // 51.2 MB
  float* el = (float*)(ws + off); off += (size_t)NN * HH * 4;   // 1.6 MB
  float* er = (float*)(ws + off); off += (size_t)NN * HH * 4;   // 1.6 MB
  int* counts    = (int*)(ws + off); off += (size_t)NN * 4;     // 200 KB (also cursor)
  int* row_start = (int*)(ws + off); off += (size_t)NN * 4;     // 200 KB
  int* partial   = (int*)(ws + off); off += 256;                // 49 used
  int* flag      = (int*)(ws + off); off += 256;
  int* s32  = (int*)(ws + off); off += (size_t)EE * 4;          // 3.2 MB
  int* d32  = (int*)(ws + off); off += (size_t)EE * 4;          // 3.2 MB
  int* csr_src = (int*)(ws + off); off += (size_t)EE * 4;       // 3.2 MB

  hipMemsetAsync(counts, 0, (size_t)NN * 4, stream);
  hipMemsetAsync(flag, 0, 4, stream);

  k_detect<<<256, 256, 0, stream>>>((const unsigned*)src_raw, (const unsigned*)dst_raw, flag);
  k_convert<<<1024, 256, 0, stream>>>(src_raw, dst_raw, flag, s32, d32);

  k_gemm<<<NN / 16, 256, 0, stream>>>(h, W, attn_w, z, el, er);

  k_hist<<<1024, 256, 0, stream>>>(d32, counts);
  const int nscan = (NN + 1023) / 1024;   // 49
  k_scan1<<<nscan, 1024, 0, stream>>>(counts, row_start, partial);
  k_scan2<<<1, 64, 0, stream>>>(partial, nscan);
  k_scan3<<<(NN + 255) / 256, 256, 0, stream>>>(row_start, partial);

  hipMemsetAsync(counts, 0, (size_t)NN * 4, stream);   // reuse as cursor
  k_scatter<<<1024, 256, 0, stream>>>(s32, d32, row_start, counts, csr_src);

  k_agg<<<NN, 256, 0, stream>>>(z, el, er, row_start, csr_src, out);
}

// Round 2
// 411.949 us; speedup vs baseline: 1.3124x; 1.3124x over previous
//
#include <hip/hip_runtime.h>
#include <math.h>

#define NN 50000
#define EE 800000
#define INDIM 256
#define DD 32
#define HH 8
#define CC 256   // H*D
#define NEG 0.01f

__device__ __forceinline__ unsigned short f32_to_bf16_rne(float f) {
  unsigned u = __float_as_uint(f);
  u += 0x7fffu + ((u >> 16) & 1u);
  return (unsigned short)(u >> 16);
}
__device__ __forceinline__ float bf16_to_f32(unsigned short b) {
  return __uint_as_float((unsigned)b << 16);
}

// ---------- index dtype probe + normalize ----------
__global__ void k_detect(const unsigned* __restrict__ s, const unsigned* __restrict__ d,
                         int* __restrict__ flag) {
  unsigned v = 0;
  int stride = gridDim.x * blockDim.x;
  for (int e = blockIdx.x * blockDim.x + threadIdx.x; e < EE / 2; e += stride)
    v |= s[2 * e + 1] | d[2 * e + 1];
  if (v) atomicOr(flag, 1);   // 1 => indices are int32
}

__global__ void k_convert(const void* __restrict__ sraw, const void* __restrict__ draw,
                          const int* __restrict__ flag,
                          int* __restrict__ s32, int* __restrict__ d32) {
  const int is32 = *flag;
  int stride = gridDim.x * blockDim.x;
  for (int e = blockIdx.x * blockDim.x + threadIdx.x; e < EE; e += stride) {
    if (is32) {
      s32[e] = ((const int*)sraw)[e];
      d32[e] = ((const int*)draw)[e];
    } else {
      s32[e] = (int)((const long long*)sraw)[e];
      d32[e] = (int)((const long long*)draw)[e];
    }
  }
}

// ---------- z = h @ W  (+ el/er epilogue); z stored bf16 ----------
__global__ __launch_bounds__(256) void k_gemm(const float* __restrict__ h,
                                              const float* __restrict__ W,
                                              const float* __restrict__ attn_w,
                                              unsigned short* __restrict__ z,
                                              float* __restrict__ el,
                                              float* __restrict__ er) {
  __shared__ float sA[16][INDIM];   // 16 KB
  const int t = threadIdx.x;
  const int row0 = blockIdx.x * 16;
  for (int r = 0; r < 16; ++r)
    sA[r][t] = h[(size_t)(row0 + r) * INDIM + t];
  __syncthreads();

  const int head = t >> 5, d = t & 31;
  const float al = attn_w[head * (2 * DD) + d];
  const float ar = attn_w[head * (2 * DD) + DD + d];
  const float* __restrict__ Bp = W + (size_t)head * INDIM * DD + d;

  float acc[16];
#pragma unroll
  for (int r = 0; r < 16; ++r) acc[r] = 0.f;

  for (int i0 = 0; i0 < INDIM; i0 += 4) {
    const float b0 = Bp[(i0 + 0) * DD];
    const float b1 = Bp[(i0 + 1) * DD];
    const float b2 = Bp[(i0 + 2) * DD];
    const float b3 = Bp[(i0 + 3) * DD];
#pragma unroll
    for (int r = 0; r < 16; ++r) {
      float4 a = *reinterpret_cast<const float4*>(&sA[r][i0]);
      acc[r] += a.x * b0 + a.y * b1 + a.z * b2 + a.w * b3;
    }
  }

#pragma unroll
  for (int r = 0; r < 16; ++r)
    z[(size_t)(row0 + r) * CC + t] = f32_to_bf16_rne(acc[r]);

  // el/er: reduce over d (32 lanes within each half-wave)
  for (int r = 0; r < 16; ++r) {
    float vl = acc[r] * al;
    float vr = acc[r] * ar;
#pragma unroll
    for (int s = 1; s < 32; s <<= 1) {
      vl += __shfl_xor(vl, s);
      vr += __shfl_xor(vr, s);
    }
    if (d == 0) {
      el[(size_t)(row0 + r) * HH + head] = vl;
      er[(size_t)(row0 + r) * HH + head] = vr;
    }
  }
}

// ---------- CSR build ----------
__global__ void k_hist(const int* __restrict__ d32, int* __restrict__ counts) {
  int stride = gridDim.x * blockDim.x;
  for (int e = blockIdx.x * blockDim.x + threadIdx.x; e < EE; e += stride)
    atomicAdd(&counts[d32[e]], 1);
}

__global__ __launch_bounds__(1024) void k_scan1(const int* __restrict__ counts,
                                                int* __restrict__ row_start,
                                                int* __restrict__ partial) {
  __shared__ int s[1024];
  const int tid = threadIdx.x;
  const int i = blockIdx.x * 1024 + tid;
  int v = (i < NN) ? counts[i] : 0;
  s[tid] = v;
  __syncthreads();
  for (int off = 1; off < 1024; off <<= 1) {
    int tv = (tid >= off) ? s[tid - off] : 0;
    __syncthreads();
    s[tid] += tv;
    __syncthreads();
  }
  if (i < NN) row_start[i] = s[tid] - v;           // exclusive
  if (tid == 1023) partial[blockIdx.x] = s[1023];  // block total
}

__global__ void k_scan2(int* __restrict__ partial, int nb) {
  if (threadIdx.x == 0 && blockIdx.x == 0) {
    int acc = 0;
    for (int i = 0; i < nb; ++i) { int t = partial[i]; partial[i] = acc; acc += t; }
  }
}

__global__ void k_scan3(int* __restrict__ row_start, const int* __restrict__ partial) {
  int i = blockIdx.x * blockDim.x + threadIdx.x;
  if (i < NN) row_start[i] += partial[i >> 10];
}

__global__ void k_scatter(const int* __restrict__ s32, const int* __restrict__ d32,
                          const int* __restrict__ row_start, int* __restrict__ cursor,
                          int* __restrict__ csr_src) {
  int stride = gridDim.x * blockDim.x;
  for (int e = blockIdx.x * blockDim.x + threadIdx.x; e < EE; e += stride) {
    int dn = d32[e];
    int pos = row_start[dn] + atomicAdd(&cursor[dn], 1);
    csr_src[pos] = s32[e];
  }
}

// ---------- per-node softmax-aggregate: ONE WAVE per node ----------
// Lane l owns columns 4l..4l+3 (head = l>>3). Pass 1: per-head max over edges.
// Pass 2: fused exp + den accumulation + bf16 z gather-accumulate (unnormalized);
// divide by den at the end.
__global__ __launch_bounds__(256) void k_agg(const unsigned short* __restrict__ z,
                                             const float* __restrict__ el,
                                             const float* __restrict__ er,
                                             const int* __restrict__ row_start,
                                             const int* __restrict__ csr_src,
                                             float* __restrict__ out) {
  const int wave = threadIdx.x >> 6;
  const int n = blockIdx.x * 4 + wave;
  const int l = threadIdx.x & 63;
  const int head = l >> 3;
  const int beg = row_start[n];
  const int end = (n == NN - 1) ? EE : row_start[n + 1];
  const float ern = er[(size_t)n * HH + head];

  float m = -INFINITY;
  for (int p = beg; p < end; ++p) {
    int s = csr_src[p];
    float v = el[(size_t)s * HH + head] + ern;
    v = (v > 0.f) ? v : v * NEG;
    m = fmaxf(m, v);
  }

  float den = 0.f;
  float a0 = 0.f, a1 = 0.f, a2 = 0.f, a3 = 0.f;
  for (int p = beg; p < end; ++p) {
    int s = csr_src[p];
    float v = el[(size_t)s * HH + head] + ern;
    v = (v > 0.f) ? v : v * NEG;
    float w = __expf(v - m);
    den += w;
    ushort4 zv = *reinterpret_cast<const ushort4*>(&z[(size_t)s * CC + 4 * l]);
    a0 += w * bf16_to_f32(zv.x);
    a1 += w * bf16_to_f32(zv.y);
    a2 += w * bf16_to_f32(zv.z);
    a3 += w * bf16_to_f32(zv.w);
  }
  const float rd = (end > beg) ? (1.f / den) : 0.f;
  float4 o;
  o.x = a0 * rd; o.y = a1 * rd; o.z = a2 * rd; o.w = a3 * rd;
  *reinterpret_cast<float4*>(&out[(size_t)n * CC + 4 * l]) = o;
}

extern "C" void kernel_launch(void* const* d_in, const int* in_sizes, int n_in,
                              void* d_out, int out_size, void* d_ws, size_t ws_size,
                              hipStream_t stream) {
  const float* h      = (const float*)d_in[0];
  const float* W      = (const float*)d_in[1];
  const float* attn_w = (const float*)d_in[2];
  const void*  src_raw = d_in[3];
  const void*  dst_raw = d_in[4];
  float* out = (float*)d_out;

  char* ws = (char*)d_ws;
  size_t off = 0;
  unsigned short* z = (unsigned short*)(ws + off); off += (size_t)NN * CC * 2;  // 25.6 MB
  float* el = (float*)(ws + off); off += (size_t)NN * HH * 4;   // 1.6 MB
  float* er = (float*)(ws + off); off += (size_t)NN * HH * 4;   // 1.6 MB
  int* counts    = (int*)(ws + off); off += (size_t)NN * 4;     // 200 KB (also cursor)
  int* row_start = (int*)(ws + off); off += (size_t)NN * 4;     // 200 KB
  int* partial   = (int*)(ws + off); off += 256;
  int* flag      = (int*)(ws + off); off += 256;
  int* s32  = (int*)(ws + off); off += (size_t)EE * 4;          // 3.2 MB
  int* d32  = (int*)(ws + off); off += (size_t)EE * 4;          // 3.2 MB
  int* csr_src = (int*)(ws + off); off += (size_t)EE * 4;       // 3.2 MB

  hipMemsetAsync(counts, 0, (size_t)NN * 4, stream);
  hipMemsetAsync(flag, 0, 4, stream);

  k_detect<<<256, 256, 0, stream>>>((const unsigned*)src_raw, (const unsigned*)dst_raw, flag);
  k_convert<<<1024, 256, 0, stream>>>(src_raw, dst_raw, flag, s32, d32);

  k_gemm<<<NN / 16, 256, 0, stream>>>(h, W, attn_w, z, el, er);

  k_hist<<<1024, 256, 0, stream>>>(d32, counts);
  const int nscan = (NN + 1023) / 1024;   // 49
  k_scan1<<<nscan, 1024, 0, stream>>>(counts, row_start, partial);
  k_scan2<<<1, 64, 0, stream>>>(partial, nscan);
  k_scan3<<<(NN + 255) / 256, 256, 0, stream>>>(row_start, partial);

  hipMemsetAsync(counts, 0, (size_t)NN * 4, stream);   // reuse as cursor
  k_scatter<<<1024, 256, 0, stream>>>(s32, d32, row_start, counts, csr_src);

  k_agg<<<NN / 4, 256, 0, stream>>>(z, el, er, row_start, csr_src, out);
}

// Round 3
// 315.314 us; speedup vs baseline: 1.7147x; 1.3065x over previous
//
#include <hip/hip_runtime.h>
#include <math.h>

#define NN 50000
#define EE 800000
#define INDIM 256
#define DD 32
#define HH 8
#define CC 256   // H*D
#define NEG 0.01f

typedef __attribute__((ext_vector_type(8))) short bf16x8;
typedef __attribute__((ext_vector_type(4))) float f32x4;

__device__ __forceinline__ unsigned short f32_to_bf16_rne(float f) {
  unsigned u = __float_as_uint(f);
  u += 0x7fffu + ((u >> 16) & 1u);
  return (unsigned short)(u >> 16);
}
__device__ __forceinline__ float bf16_to_f32(unsigned short b) {
  return __uint_as_float((unsigned)b << 16);
}

// ---------- index dtype probe + normalize ----------
__global__ void k_detect(const unsigned* __restrict__ s, const unsigned* __restrict__ d,
                         int* __restrict__ flag) {
  unsigned v = 0;
  int stride = gridDim.x * blockDim.x;
  for (int e = blockIdx.x * blockDim.x + threadIdx.x; e < EE / 2; e += stride)
    v |= s[2 * e + 1] | d[2 * e + 1];
  if (v) atomicOr(flag, 1);   // 1 => indices are int32
}

__global__ void k_convert(const void* __restrict__ sraw, const void* __restrict__ draw,
                          const int* __restrict__ flag,
                          int* __restrict__ s32, int* __restrict__ d32) {
  const int is32 = *flag;
  int stride = gridDim.x * blockDim.x;
  for (int e = blockIdx.x * blockDim.x + threadIdx.x; e < EE; e += stride) {
    if (is32) {
      s32[e] = ((const int*)sraw)[e];
      d32[e] = ((const int*)draw)[e];
    } else {
      s32[e] = (int)((const long long*)sraw)[e];
      d32[e] = (int)((const long long*)draw)[e];
    }
  }
}

// ---------- bf16 conversions ----------
__global__ void k_tobf16_h(const float* __restrict__ h, unsigned short* __restrict__ hb) {
  const int total = NN * INDIM / 8;
  int stride = gridDim.x * blockDim.x;
  for (int i = blockIdx.x * blockDim.x + threadIdx.x; i < total; i += stride) {
    float4 f0 = *reinterpret_cast<const float4*>(&h[(size_t)i * 8]);
    float4 f1 = *reinterpret_cast<const float4*>(&h[(size_t)i * 8 + 4]);
    ushort4 o0, o1;
    o0.x = f32_to_bf16_rne(f0.x); o0.y = f32_to_bf16_rne(f0.y);
    o0.z = f32_to_bf16_rne(f0.z); o0.w = f32_to_bf16_rne(f0.w);
    o1.x = f32_to_bf16_rne(f1.x); o1.y = f32_to_bf16_rne(f1.y);
    o1.z = f32_to_bf16_rne(f1.z); o1.w = f32_to_bf16_rne(f1.w);
    *reinterpret_cast<ushort4*>(&hb[(size_t)i * 8]) = o0;
    *reinterpret_cast<ushort4*>(&hb[(size_t)i * 8 + 4]) = o1;
  }
}

// WbT[n][k] = W[h][k][d], n = h*32+d  (B^T layout: frag's 8 k-elements contiguous)
__global__ void k_tobf16_w(const float* __restrict__ W, unsigned short* __restrict__ WbT) {
  int tid = blockIdx.x * blockDim.x + threadIdx.x;   // 65536 threads
  int n = tid >> 8, k = tid & 255;
  int hh = n >> 5, d = n & 31;
  WbT[tid] = f32_to_bf16_rne(W[(size_t)hh * 8192 + k * 32 + d]);
}

// ---------- z = h @ W via bf16 MFMA ----------
// Block: 256 threads = 4 waves. BM=64, BN=128 (wave w owns cols w*32..w*32+31,
// i.e. exactly one head). K=256 staged fully in LDS (XOR-swizzled); B frags in
// registers (L2-resident, loaded once).
__global__ __launch_bounds__(256) void k_gemm(const unsigned short* __restrict__ hb,
                                              const unsigned short* __restrict__ WbT,
                                              unsigned short* __restrict__ z) {
  __shared__ short sA[64 * 256];   // 32 KB, row-major [64][256], chunk-swizzled
  const int t = threadIdx.x;
  const int l = t & 63;
  const int w = t >> 6;
  const int row0 = blockIdx.x * 64;
  const int ncol0 = blockIdx.y * 128 + w * 32;

  // stage A: 2048 chunks of 16B; swizzle: chunk ^= (row & 7)
#pragma unroll
  for (int i = 0; i < 8; ++i) {
    int q = i * 256 + t;
    int row = q >> 5, c = q & 31;
    int grow = row0 + row; if (grow >= NN) grow = NN - 1;
    bf16x8 v = *reinterpret_cast<const bf16x8*>(&hb[(size_t)grow * 256 + c * 8]);
    int sc = c ^ (row & 7);
    *reinterpret_cast<bf16x8*>(&sA[row * 256 + sc * 8]) = v;
  }

  // B frags: cols ncol0 + c*16 + (l&15), k = kk*32 + (l>>4)*8 + j
  bf16x8 bf[2][8];
  {
    const int n = ncol0 + (l & 15);
    const int kb = (l >> 4) * 8;
#pragma unroll
    for (int c = 0; c < 2; ++c)
#pragma unroll
      for (int kk = 0; kk < 8; ++kk)
        bf[c][kk] = *reinterpret_cast<const bf16x8*>(
            &WbT[(size_t)(n + c * 16) * 256 + kk * 32 + kb]);
  }

  f32x4 acc[4][2];
#pragma unroll
  for (int m = 0; m < 4; ++m)
#pragma unroll
    for (int c = 0; c < 2; ++c) acc[m][c] = (f32x4){0.f, 0.f, 0.f, 0.f};

  __syncthreads();

#pragma unroll
  for (int kk = 0; kk < 8; ++kk) {
    bf16x8 af[4];
#pragma unroll
    for (int m = 0; m < 4; ++m) {
      int row = m * 16 + (l & 15);
      int chunk = kk * 4 + (l >> 4);
      int sc = chunk ^ (row & 7);
      af[m] = *reinterpret_cast<const bf16x8*>(&sA[row * 256 + sc * 8]);
    }
#pragma unroll
    for (int m = 0; m < 4; ++m)
#pragma unroll
      for (int c = 0; c < 2; ++c)
        acc[m][c] = __builtin_amdgcn_mfma_f32_16x16x32_bf16(af[m], bf[c][kk], acc[m][c], 0, 0, 0);
  }

  // store: row = row0 + m*16 + (l>>4)*4 + r ; col = ncol0 + c*16 + (l&15)
#pragma unroll
  for (int m = 0; m < 4; ++m) {
    int rowb = row0 + m * 16 + ((l >> 4) << 2);
#pragma unroll
    for (int c = 0; c < 2; ++c) {
      int col = ncol0 + c * 16 + (l & 15);
#pragma unroll
      for (int r = 0; r < 4; ++r) {
        int row = rowb + r;
        if (row < NN) z[(size_t)row * CC + col] = f32_to_bf16_rne(acc[m][c][r]);
      }
    }
  }
}

// ---------- el/er from bf16 z ----------
__global__ void k_attn(const unsigned short* __restrict__ z,
                       const float* __restrict__ attn_w,
                       float* __restrict__ el, float* __restrict__ er) {
  int tid = blockIdx.x * blockDim.x + threadIdx.x;
  if (tid >= NN * HH) return;
  int n = tid >> 3, hh = tid & 7;
  float sl = 0.f, sr = 0.f;
#pragma unroll
  for (int j = 0; j < 4; ++j) {
    bf16x8 v = *reinterpret_cast<const bf16x8*>(&z[(size_t)n * CC + hh * 32 + j * 8]);
#pragma unroll
    for (int e = 0; e < 8; ++e) {
      int d = j * 8 + e;
      float zf = bf16_to_f32((unsigned short)v[e]);
      sl += zf * attn_w[hh * 64 + d];
      sr += zf * attn_w[hh * 64 + 32 + d];
    }
  }
  el[tid] = sl;
  er[tid] = sr;
}

// ---------- CSR build ----------
__global__ void k_hist(const int* __restrict__ d32, int* __restrict__ counts) {
  int stride = gridDim.x * blockDim.x;
  for (int e = blockIdx.x * blockDim.x + threadIdx.x; e < EE; e += stride)
    atomicAdd(&counts[d32[e]], 1);
}

__global__ __launch_bounds__(1024) void k_scan1(const int* __restrict__ counts,
                                                int* __restrict__ row_start,
                                                int* __restrict__ partial) {
  __shared__ int s[1024];
  const int tid = threadIdx.x;
  const int i = blockIdx.x * 1024 + tid;
  int v = (i < NN) ? counts[i] : 0;
  s[tid] = v;
  __syncthreads();
  for (int off = 1; off < 1024; off <<= 1) {
    int tv = (tid >= off) ? s[tid - off] : 0;
    __syncthreads();
    s[tid] += tv;
    __syncthreads();
  }
  if (i < NN) row_start[i] = s[tid] - v;           // exclusive
  if (tid == 1023) partial[blockIdx.x] = s[1023];  // block total
}

__global__ void k_scan2(int* __restrict__ partial, int nb) {
  if (threadIdx.x == 0 && blockIdx.x == 0) {
    int acc = 0;
    for (int i = 0; i < nb; ++i) { int t = partial[i]; partial[i] = acc; acc += t; }
  }
}

__global__ void k_scan3(int* __restrict__ row_start, const int* __restrict__ partial) {
  int i = blockIdx.x * blockDim.x + threadIdx.x;
  if (i < NN) row_start[i] += partial[i >> 10];
}

__global__ void k_scatter(const int* __restrict__ s32, const int* __restrict__ d32,
                          const int* __restrict__ row_start, int* __restrict__ cursor,
                          int* __restrict__ csr_src) {
  int stride = gridDim.x * blockDim.x;
  for (int e = blockIdx.x * blockDim.x + threadIdx.x; e < EE; e += stride) {
    int dn = d32[e];
    int pos = row_start[dn] + atomicAdd(&cursor[dn], 1);
    csr_src[pos] = s32[e];
  }
}

// ---------- per-node softmax-aggregate: ONE WAVE per node ----------
__global__ __launch_bounds__(256) void k_agg(const unsigned short* __restrict__ z,
                                             const float* __restrict__ el,
                                             const float* __restrict__ er,
                                             const int* __restrict__ row_start,
                                             const int* __restrict__ csr_src,
                                             float* __restrict__ out) {
  const int wave = threadIdx.x >> 6;
  const int n = blockIdx.x * 4 + wave;
  const int l = threadIdx.x & 63;
  const int head = l >> 3;
  const int beg = row_start[n];
  const int end = (n == NN - 1) ? EE : row_start[n + 1];
  const float ern = er[(size_t)n * HH + head];

  float m = -INFINITY;
  for (int p = beg; p < end; ++p) {
    int s = csr_src[p];
    float v = el[(size_t)s * HH + head] + ern;
    v = (v > 0.f) ? v : v * NEG;
    m = fmaxf(m, v);
  }

  float den = 0.f;
  float a0 = 0.f, a1 = 0.f, a2 = 0.f, a3 = 0.f;
  for (int p = beg; p < end; ++p) {
    int s = csr_src[p];
    float v = el[(size_t)s * HH + head] + ern;
    v = (v > 0.f) ? v : v * NEG;
    float w = __expf(v - m);
    den += w;
    ushort4 zv = *reinterpret_cast<const ushort4*>(&z[(size_t)s * CC + 4 * l]);
    a0 += w * bf16_to_f32(zv.x);
    a1 += w * bf16_to_f32(zv.y);
    a2 += w * bf16_to_f32(zv.z);
    a3 += w * bf16_to_f32(zv.w);
  }
  const float rd = (end > beg) ? (1.f / den) : 0.f;
  float4 o;
  o.x = a0 * rd; o.y = a1 * rd; o.z = a2 * rd; o.w = a3 * rd;
  *reinterpret_cast<float4*>(&out[(size_t)n * CC + 4 * l]) = o;
}

extern "C" void kernel_launch(void* const* d_in, const int* in_sizes, int n_in,
                              void* d_out, int out_size, void* d_ws, size_t ws_size,
                              hipStream_t stream) {
  const float* h      = (const float*)d_in[0];
  const float* W      = (const float*)d_in[1];
  const float* attn_w = (const float*)d_in[2];
  const void*  src_raw = d_in[3];
  const void*  dst_raw = d_in[4];
  float* out = (float*)d_out;

  char* ws = (char*)d_ws;
  size_t off = 0;
  unsigned short* z  = (unsigned short*)(ws + off); off += (size_t)NN * CC * 2;     // 25.6 MB
  unsigned short* hb = (unsigned short*)(ws + off); off += (size_t)NN * INDIM * 2;  // 25.6 MB
  unsigned short* WbT = (unsigned short*)(ws + off); off += (size_t)INDIM * CC * 2; // 128 KB
  float* el = (float*)(ws + off); off += (size_t)NN * HH * 4;   // 1.6 MB
  float* er = (float*)(ws + off); off += (size_t)NN * HH * 4;   // 1.6 MB
  int* counts    = (int*)(ws + off); off += (size_t)NN * 4;     // 200 KB (also cursor)
  int* row_start = (int*)(ws + off); off += (size_t)NN * 4;     // 200 KB
  int* partial   = (int*)(ws + off); off += 256;
  int* flag      = (int*)(ws + off); off += 256;
  int* s32  = (int*)(ws + off); off += (size_t)EE * 4;          // 3.2 MB
  int* d32  = (int*)(ws + off); off += (size_t)EE * 4;          // 3.2 MB
  int* csr_src = (int*)(ws + off); off += (size_t)EE * 4;       // 3.2 MB

  hipMemsetAsync(counts, 0, (size_t)NN * 4, stream);
  hipMemsetAsync(flag, 0, 4, stream);

  k_detect<<<256, 256, 0, stream>>>((const unsigned*)src_raw, (const unsigned*)dst_raw, flag);
  k_convert<<<1024, 256, 0, stream>>>(src_raw, dst_raw, flag, s32, d32);

  k_tobf16_h<<<2048, 256, 0, stream>>>(h, hb);
  k_tobf16_w<<<256, 256, 0, stream>>>(W, WbT);

  dim3 ggrid((NN + 63) / 64, 2);
  k_gemm<<<ggrid, 256, 0, stream>>>(hb, WbT, z);
  k_attn<<<(NN * HH + 255) / 256, 256, 0, stream>>>(z, attn_w, el, er);

  k_hist<<<1024, 256, 0, stream>>>(d32, counts);
  const int nscan = (NN + 1023) / 1024;   // 49
  k_scan1<<<nscan, 1024, 0, stream>>>(counts, row_start, partial);
  k_scan2<<<1, 64, 0, stream>>>(partial, nscan);
  k_scan3<<<(NN + 255) / 256, 256, 0, stream>>>(row_start, partial);

  hipMemsetAsync(counts, 0, (size_t)NN * 4, stream);   // reuse as cursor
  k_scatter<<<1024, 256, 0, stream>>>(s32, d32, row_start, counts, csr_src);

  k_agg<<<NN / 4, 256, 0, stream>>>(z, el, er, row_start, csr_src, out);
}

// Round 4
// 235.325 us; speedup vs baseline: 2.2975x; 1.3399x over previous
//
#include <hip/hip_runtime.h>
#include <math.h>

#define NN 50000
#define EE 800000
#define INDIM 256
#define DD 32
#define HH 8
#define CC 256   // H*D
#define NEG 0.01f

typedef __attribute__((ext_vector_type(8))) short bf16x8;
typedef __attribute__((ext_vector_type(4))) float f32x4;

__device__ __forceinline__ unsigned short f32_to_bf16_rne(float f) {
  unsigned u = __float_as_uint(f);
  u += 0x7fffu + ((u >> 16) & 1u);
  return (unsigned short)(u >> 16);
}
__device__ __forceinline__ float bf16_to_f32(unsigned short b) {
  return __uint_as_float((unsigned)b << 16);
}

// ---------- index dtype probe ----------
__global__ void k_detect(const unsigned* __restrict__ s, const unsigned* __restrict__ d,
                         int* __restrict__ flag) {
  unsigned v = 0;
  int stride = gridDim.x * blockDim.x;
  for (int e = blockIdx.x * blockDim.x + threadIdx.x; e < EE / 2; e += stride)
    v |= s[2 * e + 1] | d[2 * e + 1];
  if (v) atomicOr(flag, 1);   // 1 => indices are int32
}

// ---------- convert + histogram (fused) ----------
__global__ void k_convert(const void* __restrict__ sraw, const void* __restrict__ draw,
                          const int* __restrict__ flag,
                          int* __restrict__ s32, int* __restrict__ d32,
                          int* __restrict__ counts) {
  const int is32 = *flag;
  int stride = gridDim.x * blockDim.x;
  for (int e = blockIdx.x * blockDim.x + threadIdx.x; e < EE; e += stride) {
    int sv, dv;
    if (is32) {
      sv = ((const int*)sraw)[e];
      dv = ((const int*)draw)[e];
    } else {
      sv = (int)((const long long*)sraw)[e];
      dv = (int)((const long long*)draw)[e];
    }
    s32[e] = sv;
    d32[e] = dv;
    atomicAdd(&counts[dv], 1);
  }
}

// WbT[n][k] = W[h][k][d], n = h*32+d  (B^T layout: frag's 8 k-elements contiguous)
__global__ void k_tobf16_w(const float* __restrict__ W, unsigned short* __restrict__ WbT) {
  int tid = blockIdx.x * blockDim.x + threadIdx.x;   // 65536 threads
  int n = tid >> 8, k = tid & 255;
  int hh = n >> 5, d = n & 31;
  WbT[tid] = f32_to_bf16_rne(W[(size_t)hh * 8192 + k * 32 + d]);
}

// ---------- z = h @ W via bf16 MFMA, el/er fused in epilogue ----------
// Block: 512 threads = 8 waves; wave w == head w (cols w*32..w*32+31). BM=64,
// BN=256, K=256 fully staged in LDS (XOR-swizzled); h converted f32->bf16
// in-register during staging; B frags in registers (L2-resident).
__global__ __launch_bounds__(512) void k_gemm(const float* __restrict__ h,
                                              const unsigned short* __restrict__ WbT,
                                              const float* __restrict__ attn_w,
                                              unsigned short* __restrict__ z,
                                              float* __restrict__ el,
                                              float* __restrict__ er) {
  __shared__ short sA[64 * 256];   // 32 KB, row-major [64][256], chunk-swizzled
  const int t = threadIdx.x;
  const int l = t & 63;
  const int w = t >> 6;            // wave index == head
  const int row0 = blockIdx.x * 64;

  // stage A: 2048 chunks of 8 bf16; 512 threads x 4 chunks. swizzle: chunk ^= (row&7)
#pragma unroll
  for (int i = 0; i < 4; ++i) {
    int q = i * 512 + t;
    int row = q >> 5, c = q & 31;
    int grow = row0 + row; if (grow >= NN) grow = NN - 1;
    const float* src = &h[(size_t)grow * 256 + c * 8];
    float4 f0 = *reinterpret_cast<const float4*>(src);
    float4 f1 = *reinterpret_cast<const float4*>(src + 4);
    bf16x8 v;
    v[0] = (short)f32_to_bf16_rne(f0.x); v[1] = (short)f32_to_bf16_rne(f0.y);
    v[2] = (short)f32_to_bf16_rne(f0.z); v[3] = (short)f32_to_bf16_rne(f0.w);
    v[4] = (short)f32_to_bf16_rne(f1.x); v[5] = (short)f32_to_bf16_rne(f1.y);
    v[6] = (short)f32_to_bf16_rne(f1.z); v[7] = (short)f32_to_bf16_rne(f1.w);
    int sc = c ^ (row & 7);
    *reinterpret_cast<bf16x8*>(&sA[row * 256 + sc * 8]) = v;
  }

  // B frags: cols w*32 + c*16 + (l&15), k = kk*32 + (l>>4)*8 + j
  bf16x8 bf[2][8];
  {
    const int n = w * 32 + (l & 15);
    const int kb = (l >> 4) * 8;
#pragma unroll
    for (int c = 0; c < 2; ++c)
#pragma unroll
      for (int kk = 0; kk < 8; ++kk)
        bf[c][kk] = *reinterpret_cast<const bf16x8*>(
            &WbT[(size_t)(n + c * 16) * 256 + kk * 32 + kb]);
  }

  f32x4 acc[4][2];
#pragma unroll
  for (int m = 0; m < 4; ++m)
#pragma unroll
    for (int c = 0; c < 2; ++c) acc[m][c] = (f32x4){0.f, 0.f, 0.f, 0.f};

  __syncthreads();

#pragma unroll
  for (int kk = 0; kk < 8; ++kk) {
    bf16x8 af[4];
#pragma unroll
    for (int m = 0; m < 4; ++m) {
      int row = m * 16 + (l & 15);
      int chunk = kk * 4 + (l >> 4);
      int sc = chunk ^ (row & 7);
      af[m] = *reinterpret_cast<const bf16x8*>(&sA[row * 256 + sc * 8]);
    }
#pragma unroll
    for (int m = 0; m < 4; ++m)
#pragma unroll
      for (int c = 0; c < 2; ++c)
        acc[m][c] = __builtin_amdgcn_mfma_f32_16x16x32_bf16(af[m], bf[c][kk], acc[m][c], 0, 0, 0);
  }

  // store z: row = row0 + m*16 + (l>>4)*4 + r ; col = w*32 + c*16 + (l&15)
#pragma unroll
  for (int m = 0; m < 4; ++m) {
    int rowb = row0 + m * 16 + ((l >> 4) << 2);
#pragma unroll
    for (int c = 0; c < 2; ++c) {
      int col = w * 32 + c * 16 + (l & 15);
#pragma unroll
      for (int r = 0; r < 4; ++r) {
        int row = rowb + r;
        if (row < NN) z[(size_t)row * CC + col] = f32_to_bf16_rne(acc[m][c][r]);
      }
    }
  }

  // el/er epilogue from f32 accs: reduce over d (cols of this head) =
  // 2 c-terms per lane + 16-lane xor-reduce within each quarter-wave.
  const float al0 = attn_w[w * 64 + (l & 15)];
  const float al1 = attn_w[w * 64 + 16 + (l & 15)];
  const float ar0 = attn_w[w * 64 + 32 + (l & 15)];
  const float ar1 = attn_w[w * 64 + 48 + (l & 15)];
#pragma unroll
  for (int m = 0; m < 4; ++m) {
#pragma unroll
    for (int r = 0; r < 4; ++r) {
      float pl = acc[m][0][r] * al0 + acc[m][1][r] * al1;
      float pr = acc[m][0][r] * ar0 + acc[m][1][r] * ar1;
#pragma unroll
      for (int s = 1; s < 16; s <<= 1) {
        pl += __shfl_xor(pl, s);
        pr += __shfl_xor(pr, s);
      }
      if ((l & 15) == 0) {
        int row = row0 + m * 16 + ((l >> 4) << 2) + r;
        if (row < NN) {
          el[(size_t)row * HH + w] = pl;
          er[(size_t)row * HH + w] = pr;
        }
      }
    }
  }
}

// ---------- scan (exclusive prefix sum of counts) ----------
__global__ __launch_bounds__(1024) void k_scan1(const int* __restrict__ counts,
                                                int* __restrict__ row_start,
                                                int* __restrict__ partial) {
  __shared__ int s[1024];
  const int tid = threadIdx.x;
  const int i = blockIdx.x * 1024 + tid;
  int v = (i < NN) ? counts[i] : 0;
  s[tid] = v;
  __syncthreads();
  for (int off = 1; off < 1024; off <<= 1) {
    int tv = (tid >= off) ? s[tid - off] : 0;
    __syncthreads();
    s[tid] += tv;
    __syncthreads();
  }
  if (i < NN) row_start[i] = s[tid] - v;           // exclusive
  if (tid == 1023) partial[blockIdx.x] = s[1023];  // block total
}

__global__ void k_scan2(int* __restrict__ partial, int nb) {
  if (threadIdx.x == 0 && blockIdx.x == 0) {
    int acc = 0;
    for (int i = 0; i < nb; ++i) { int t = partial[i]; partial[i] = acc; acc += t; }
  }
}

// adds block offsets; also emits cursor = row_start (scatter's atomic base)
__global__ void k_scan3(int* __restrict__ row_start, const int* __restrict__ partial,
                        int* __restrict__ cursor) {
  int i = blockIdx.x * blockDim.x + threadIdx.x;
  if (i < NN) {
    int v = row_start[i] + partial[i >> 10];
    row_start[i] = v;
    cursor[i] = v;
  }
}

__global__ void k_scatter(const int* __restrict__ s32, const int* __restrict__ d32,
                          int* __restrict__ cursor, int* __restrict__ csr_src) {
  int stride = gridDim.x * blockDim.x;
  for (int e = blockIdx.x * blockDim.x + threadIdx.x; e < EE; e += stride) {
    int dn = d32[e];
    int pos = atomicAdd(&cursor[dn], 1);
    csr_src[pos] = s32[e];
  }
}

// ---------- per-node softmax-aggregate: single pass (m=0), persistent waves ----------
// softmax is shift-invariant; |e| <~ 2.5 here so exp without max-shift is exact
// softmax modulo fp rounding. Lane l owns columns 4l..4l+3 (head = l>>3).
#define AGG_WAVES 8192
__global__ __launch_bounds__(256) void k_agg(const unsigned short* __restrict__ z,
                                             const float* __restrict__ el,
                                             const float* __restrict__ er,
                                             const int* __restrict__ row_start,
                                             const int* __restrict__ csr_src,
                                             float* __restrict__ out) {
  const int gw = blockIdx.x * 4 + (threadIdx.x >> 6);
  const int l = threadIdx.x & 63;
  const int head = l >> 3;

  for (int n = gw; n < NN; n += AGG_WAVES) {
    const int beg = row_start[n];
    const int end = (n == NN - 1) ? EE : row_start[n + 1];
    const float ern = er[(size_t)n * HH + head];

    float den = 0.f;
    float a0 = 0.f, a1 = 0.f, a2 = 0.f, a3 = 0.f;
#pragma unroll 4
    for (int p = beg; p < end; ++p) {
      int s = csr_src[p];
      float v = el[(size_t)s * HH + head] + ern;
      v = (v > 0.f) ? v : v * NEG;
      float wgt = __expf(v);
      ushort4 zv = *reinterpret_cast<const ushort4*>(&z[(size_t)s * CC + 4 * l]);
      den += wgt;
      a0 += wgt * bf16_to_f32(zv.x);
      a1 += wgt * bf16_to_f32(zv.y);
      a2 += wgt * bf16_to_f32(zv.z);
      a3 += wgt * bf16_to_f32(zv.w);
    }
    const float rd = (end > beg) ? (1.f / den) : 0.f;
    float4 o;
    o.x = a0 * rd; o.y = a1 * rd; o.z = a2 * rd; o.w = a3 * rd;
    *reinterpret_cast<float4*>(&out[(size_t)n * CC + 4 * l]) = o;
  }
}

extern "C" void kernel_launch(void* const* d_in, const int* in_sizes, int n_in,
                              void* d_out, int out_size, void* d_ws, size_t ws_size,
                              hipStream_t stream) {
  const float* h      = (const float*)d_in[0];
  const float* W      = (const float*)d_in[1];
  const float* attn_w = (const float*)d_in[2];
  const void*  src_raw = d_in[3];
  const void*  dst_raw = d_in[4];
  float* out = (float*)d_out;

  char* ws = (char*)d_ws;
  size_t off = 0;
  unsigned short* z   = (unsigned short*)(ws + off); off += (size_t)NN * CC * 2;     // 25.6 MB
  unsigned short* WbT = (unsigned short*)(ws + off); off += (size_t)INDIM * CC * 2;  // 128 KB
  float* el = (float*)(ws + off); off += (size_t)NN * HH * 4;   // 1.6 MB
  float* er = (float*)(ws + off); off += (size_t)NN * HH * 4;   // 1.6 MB
  int* counts    = (int*)(ws + off); off += (size_t)NN * 4;     // 200 KB
  int* flag      = (int*)(ws + off); off += 256;                // memset with counts
  int* row_start = (int*)(ws + off); off += (size_t)NN * 4;
  int* cursor    = (int*)(ws + off); off += (size_t)NN * 4;
  int* partial   = (int*)(ws + off); off += 256;
  int* s32  = (int*)(ws + off); off += (size_t)EE * 4;          // 3.2 MB
  int* d32  = (int*)(ws + off); off += (size_t)EE * 4;          // 3.2 MB
  int* csr_src = (int*)(ws + off); off += (size_t)EE * 4;       // 3.2 MB

  hipMemsetAsync(counts, 0, (size_t)NN * 4 + 256, stream);   // counts + flag

  k_detect<<<256, 256, 0, stream>>>((const unsigned*)src_raw, (const unsigned*)dst_raw, flag);
  k_convert<<<1024, 256, 0, stream>>>(src_raw, dst_raw, flag, s32, d32, counts);

  k_tobf16_w<<<256, 256, 0, stream>>>(W, WbT);
  k_gemm<<<(NN + 63) / 64, 512, 0, stream>>>(h, WbT, attn_w, z, el, er);

  const int nscan = (NN + 1023) / 1024;   // 49
  k_scan1<<<nscan, 1024, 0, stream>>>(counts, row_start, partial);
  k_scan2<<<1, 64, 0, stream>>>(partial, nscan);
  k_scan3<<<(NN + 255) / 256, 256, 0, stream>>>(row_start, partial, cursor);

  k_scatter<<<1024, 256, 0, stream>>>(s32, d32, cursor, csr_src);

  k_agg<<<AGG_WAVES / 4, 256, 0, stream>>>(z, el, er, row_start, csr_src, out);
}

// Round 5
// 210.091 us; speedup vs baseline: 2.5734x; 1.1201x over previous
//
#include <hip/hip_runtime.h>
#include <math.h>

#define NN 50000
#define EE 800000
#define INDIM 256
#define DD 32
#define HH 8
#define CC 256   // H*D
#define NEG 0.01f

typedef __attribute__((ext_vector_type(8))) short bf16x8;
typedef __attribute__((ext_vector_type(4))) float f32x4;

__device__ __forceinline__ unsigned short f32_to_bf16_rne(float f) {
  unsigned u = __float_as_uint(f);
  u += 0x7fffu + ((u >> 16) & 1u);
  return (unsigned short)(u >> 16);
}
__device__ __forceinline__ float bf16_to_f32(unsigned short b) {
  return __uint_as_float((unsigned)b << 16);
}

// ---------- fused: dtype-detect + convert + histogram + W->bf16 ----------
// Per-block detect: sample 1024 odd 32-bit words in [0, EE) word range. int64
// layout -> all high words zero; int32 layout -> words are random node ids
// (P(all zero) ~ (2e-5)^2048 = 0).
__global__ __launch_bounds__(256) void k_prep(const unsigned* __restrict__ sraw,
                                              const unsigned* __restrict__ draw,
                                              int* __restrict__ s32, int* __restrict__ d32,
                                              int* __restrict__ counts,
                                              const float* __restrict__ W,
                                              unsigned short* __restrict__ WbT) {
  __shared__ int sflag;
  if (threadIdx.x == 0) sflag = 0;
  __syncthreads();
  const int gt = blockIdx.x * 256 + threadIdx.x;
  unsigned v = 0;
#pragma unroll
  for (int i = 0; i < 4; ++i) {
    int e = (gt * 4 + i) % (EE / 2);
    v |= sraw[2 * e + 1] | draw[2 * e + 1];
  }
  if (v) atomicOr(&sflag, 1);
  __syncthreads();
  const int is32 = sflag;   // 1 => int32 indices

  const int stride = gridDim.x * blockDim.x;
  for (int e = gt; e < EE; e += stride) {
    int sv, dv;
    if (is32) {
      sv = ((const int*)sraw)[e];
      dv = ((const int*)draw)[e];
    } else {
      sv = (int)((const long long*)sraw)[e];
      dv = (int)((const long long*)draw)[e];
    }
    s32[e] = sv;
    d32[e] = dv;
    atomicAdd(&counts[dv], 1);
  }

  // W -> WbT[n][k] = W[h][k][d], n=h*32+d (B^T layout)
  if (gt < INDIM * CC) {
    int n = gt >> 8, k = gt & 255;
    int hh = n >> 5, d = n & 31;
    WbT[gt] = f32_to_bf16_rne(W[(size_t)hh * 8192 + k * 32 + d]);
  }
}

// ---------- z = h @ W via bf16 MFMA (swapped operands => z-tile transposed in
// regs: lane holds 4 consecutive feats of one node). el/er fused in epilogue.
// 512 threads = 8 waves; wave w == head w. BM=64 nodes, K=256 in LDS.
__global__ __launch_bounds__(512) void k_gemm(const float* __restrict__ h,
                                              const unsigned short* __restrict__ WbT,
                                              const float* __restrict__ attn_w,
                                              unsigned short* __restrict__ z,
                                              float* __restrict__ el,
                                              float* __restrict__ er) {
  __shared__ short sA[64 * 256];   // 32 KB, [64 nodes][256 k], chunk-swizzled
  const int t = threadIdx.x;
  const int l = t & 63;
  const int w = t >> 6;            // wave index == head
  const int row0 = blockIdx.x * 64;

  // stage A (h rows, f32 -> bf16 in-register): 2048 chunks of 8; swizzle chunk ^= row&7
#pragma unroll
  for (int i = 0; i < 4; ++i) {
    int q = i * 512 + t;
    int row = q >> 5, c = q & 31;
    int grow = row0 + row; if (grow >= NN) grow = NN - 1;
    const float* src = &h[(size_t)grow * 256 + c * 8];
    float4 f0 = *reinterpret_cast<const float4*>(src);
    float4 f1 = *reinterpret_cast<const float4*>(src + 4);
    bf16x8 vv;
    vv[0] = (short)f32_to_bf16_rne(f0.x); vv[1] = (short)f32_to_bf16_rne(f0.y);
    vv[2] = (short)f32_to_bf16_rne(f0.z); vv[3] = (short)f32_to_bf16_rne(f0.w);
    vv[4] = (short)f32_to_bf16_rne(f1.x); vv[5] = (short)f32_to_bf16_rne(f1.y);
    vv[6] = (short)f32_to_bf16_rne(f1.z); vv[7] = (short)f32_to_bf16_rne(f1.w);
    int sc = c ^ (row & 7);
    *reinterpret_cast<bf16x8*>(&sA[row * 256 + sc * 8]) = vv;
  }

  // W frags (used as MFMA *A* operand): row n = w*32 + c*16 + (l&15), k = kk*32+(l>>4)*8+j
  bf16x8 bf[2][8];
  {
    const int n = w * 32 + (l & 15);
    const int kb = (l >> 4) * 8;
#pragma unroll
    for (int c = 0; c < 2; ++c)
#pragma unroll
      for (int kk = 0; kk < 8; ++kk)
        bf[c][kk] = *reinterpret_cast<const bf16x8*>(
            &WbT[(size_t)(n + c * 16) * 256 + kk * 32 + kb]);
  }

  f32x4 acc[4][2];
#pragma unroll
  for (int m = 0; m < 4; ++m)
#pragma unroll
    for (int c = 0; c < 2; ++c) acc[m][c] = (f32x4){0.f, 0.f, 0.f, 0.f};

  __syncthreads();

#pragma unroll
  for (int kk = 0; kk < 8; ++kk) {
    bf16x8 af[4];
#pragma unroll
    for (int m = 0; m < 4; ++m) {
      int row = m * 16 + (l & 15);
      int chunk = kk * 4 + (l >> 4);
      int sc = chunk ^ (row & 7);
      af[m] = *reinterpret_cast<const bf16x8*>(&sA[row * 256 + sc * 8]);
    }
    // D^T = B^T * A^T : pass W-frag as A, h-frag as B.
#pragma unroll
    for (int m = 0; m < 4; ++m)
#pragma unroll
      for (int c = 0; c < 2; ++c)
        acc[m][c] = __builtin_amdgcn_mfma_f32_16x16x32_bf16(bf[c][kk], af[m], acc[m][c], 0, 0, 0);
  }

  // acc[m][c][r]: node = row0+m*16+(l&15), feat = w*32 + c*16 + (l>>4)*4 + r
#pragma unroll
  for (int m = 0; m < 4; ++m) {
    int node = row0 + m * 16 + (l & 15);
    if (node < NN) {
#pragma unroll
      for (int c = 0; c < 2; ++c) {
        ushort4 pk;
        pk.x = f32_to_bf16_rne(acc[m][c][0]);
        pk.y = f32_to_bf16_rne(acc[m][c][1]);
        pk.z = f32_to_bf16_rne(acc[m][c][2]);
        pk.w = f32_to_bf16_rne(acc[m][c][3]);
        *reinterpret_cast<ushort4*>(
            &z[(size_t)node * CC + w * 32 + c * 16 + ((l >> 4) << 2)]) = pk;
      }
    }
  }

  // el/er epilogue: lane's 8 feats have d = c*16 + (l>>4)*4 + r within head.
  float alc[2][4], arc[2][4];
#pragma unroll
  for (int c = 0; c < 2; ++c)
#pragma unroll
    for (int r = 0; r < 4; ++r) {
      int d = c * 16 + ((l >> 4) << 2) + r;
      alc[c][r] = attn_w[w * 64 + d];
      arc[c][r] = attn_w[w * 64 + 32 + d];
    }
#pragma unroll
  for (int m = 0; m < 4; ++m) {
    float pl = 0.f, pr = 0.f;
#pragma unroll
    for (int c = 0; c < 2; ++c)
#pragma unroll
      for (int r = 0; r < 4; ++r) {
        pl += acc[m][c][r] * alc[c][r];
        pr += acc[m][c][r] * arc[c][r];
      }
    pl += __shfl_xor(pl, 16); pl += __shfl_xor(pl, 32);
    pr += __shfl_xor(pr, 16); pr += __shfl_xor(pr, 32);
    if ((l >> 4) == 0) {
      int node = row0 + m * 16 + l;
      if (node < NN) {
        el[(size_t)node * HH + w] = pl;
        er[(size_t)node * HH + w] = pr;
      }
    }
  }
}

// ---------- scan ----------
__global__ __launch_bounds__(1024) void k_scan1(const int* __restrict__ counts,
                                                int* __restrict__ row_start,
                                                int* __restrict__ partial) {
  __shared__ int s[1024];
  const int tid = threadIdx.x;
  const int i = blockIdx.x * 1024 + tid;
  int v = (i < NN) ? counts[i] : 0;
  s[tid] = v;
  __syncthreads();
  for (int off = 1; off < 1024; off <<= 1) {
    int tv = (tid >= off) ? s[tid - off] : 0;
    __syncthreads();
    s[tid] += tv;
    __syncthreads();
  }
  if (i < NN) row_start[i] = s[tid] - v;           // exclusive
  if (tid == 1023) partial[blockIdx.x] = s[1023];  // block total
}

// one wave, parallel exclusive scan of <=64 partials
__global__ void k_scan2(int* __restrict__ partial, int nb) {
  int l = threadIdx.x & 63;
  int x = (l < nb) ? partial[l] : 0;
  int orig = x;
#pragma unroll
  for (int off = 1; off < 64; off <<= 1) {
    int y = __shfl_up(x, off);
    if (l >= off) x += y;
  }
  if (l < nb) partial[l] = x - orig;
}

__global__ void k_scan3(int* __restrict__ row_start, const int* __restrict__ partial,
                        int* __restrict__ cursor) {
  int i = blockIdx.x * blockDim.x + threadIdx.x;
  if (i < NN) {
    int v = row_start[i] + partial[i >> 10];
    row_start[i] = v;
    cursor[i] = v;
  }
}

__global__ void k_scatter(const int* __restrict__ s32, const int* __restrict__ d32,
                          int* __restrict__ cursor, int* __restrict__ csr_src) {
  int stride = gridDim.x * blockDim.x;
  for (int e = blockIdx.x * blockDim.x + threadIdx.x; e < EE; e += stride) {
    int dn = d32[e];
    int pos = atomicAdd(&cursor[dn], 1);
    csr_src[pos] = s32[e];
  }
}

// ---------- per-node softmax-aggregate: 64-edge LDS batches ----------
// Per 64-edge chunk: coalesced csr load; each lane computes ALL 8 head weights
// for ITS edge (el row gather, 32B); weights (f32) + src cached in wave-private
// LDS. Inner loop per edge: 2 LDS broadcasts + z gather + 4 FMA. m=0 softmax
// (|e| <~ 2.5, exp safe in f32; softmax shift-invariant).
#define AGG_WAVES 8192
__global__ __launch_bounds__(256) void k_agg(const unsigned short* __restrict__ z,
                                             const float* __restrict__ el,
                                             const float* __restrict__ er,
                                             const int* __restrict__ row_start,
                                             const int* __restrict__ csr_src,
                                             float* __restrict__ out) {
  __shared__ float swgt[4][64 * 8];   // [wave][edge][head], read (jj*8+head): 8 banks, bcast
  __shared__ int ssrc[4][64];
  const int wid = threadIdx.x >> 6;
  const int gw = blockIdx.x * 4 + wid;
  const int l = threadIdx.x & 63;
  const int head = l >> 3;
  float* __restrict__ wgt_l = swgt[wid];
  int* __restrict__ src_l = ssrc[wid];

  for (int n = gw; n < NN; n += AGG_WAVES) {
    const int beg = row_start[n];
    const int end = (n == NN - 1) ? EE : row_start[n + 1];
    float4 er0 = *reinterpret_cast<const float4*>(&er[(size_t)n * 8]);
    float4 er1 = *reinterpret_cast<const float4*>(&er[(size_t)n * 8 + 4]);

    float den = 0.f;
    float a0 = 0.f, a1 = 0.f, a2 = 0.f, a3 = 0.f;

    for (int base = beg; base < end; base += 64) {
      int cnt = end - base; if (cnt > 64) cnt = 64;
      int p = base + l;
      int s = csr_src[(p < end) ? p : (end - 1)];
      float4 e0 = *reinterpret_cast<const float4*>(&el[(size_t)s * 8]);
      float4 e1 = *reinterpret_cast<const float4*>(&el[(size_t)s * 8 + 4]);
      float4 w0, w1;
      {
        float v;
        v = e0.x + er0.x; v = (v > 0.f) ? v : v * NEG; w0.x = __expf(v);
        v = e0.y + er0.y; v = (v > 0.f) ? v : v * NEG; w0.y = __expf(v);
        v = e0.z + er0.z; v = (v > 0.f) ? v : v * NEG; w0.z = __expf(v);
        v = e0.w + er0.w; v = (v > 0.f) ? v : v * NEG; w0.w = __expf(v);
        v = e1.x + er1.x; v = (v > 0.f) ? v : v * NEG; w1.x = __expf(v);
        v = e1.y + er1.y; v = (v > 0.f) ? v : v * NEG; w1.y = __expf(v);
        v = e1.z + er1.z; v = (v > 0.f) ? v : v * NEG; w1.z = __expf(v);
        v = e1.w + er1.w; v = (v > 0.f) ? v : v * NEG; w1.w = __expf(v);
      }
      *reinterpret_cast<float4*>(&wgt_l[l * 8]) = w0;
      *reinterpret_cast<float4*>(&wgt_l[l * 8 + 4]) = w1;
      src_l[l] = s;
      // wave-private LDS: no barrier needed; compiler inserts lgkmcnt waits.
#pragma unroll 4
      for (int jj = 0; jj < cnt; ++jj) {
        int s_jj = src_l[jj];               // same-address broadcast
        float wgt = wgt_l[jj * 8 + head];   // 8 banks, 8-lane broadcast each
        den += wgt;
        ushort4 zv = *reinterpret_cast<const ushort4*>(&z[(size_t)s_jj * CC + 4 * l]);
        a0 += wgt * bf16_to_f32(zv.x);
        a1 += wgt * bf16_to_f32(zv.y);
        a2 += wgt * bf16_to_f32(zv.z);
        a3 += wgt * bf16_to_f32(zv.w);
      }
    }
    const float rd = (end > beg) ? (1.f / den) : 0.f;
    float4 o;
    o.x = a0 * rd; o.y = a1 * rd; o.z = a2 * rd; o.w = a3 * rd;
    *reinterpret_cast<float4*>(&out[(size_t)n * CC + 4 * l]) = o;
  }
}

extern "C" void kernel_launch(void* const* d_in, const int* in_sizes, int n_in,
                              void* d_out, int out_size, void* d_ws, size_t ws_size,
                              hipStream_t stream) {
  const float* h      = (const float*)d_in[0];
  const float* W      = (const float*)d_in[1];
  const float* attn_w = (const float*)d_in[2];
  const void*  src_raw = d_in[3];
  const void*  dst_raw = d_in[4];
  float* out = (float*)d_out;

  char* ws = (char*)d_ws;
  size_t off = 0;
  unsigned short* z   = (unsigned short*)(ws + off); off += (size_t)NN * CC * 2;     // 25.6 MB
  unsigned short* WbT = (unsigned short*)(ws + off); off += (size_t)INDIM * CC * 2;  // 128 KB
  float* el = (float*)(ws + off); off += (size_t)NN * HH * 4;   // 1.6 MB
  float* er = (float*)(ws + off); off += (size_t)NN * HH * 4;   // 1.6 MB
  int* counts    = (int*)(ws + off); off += (size_t)NN * 4;     // 200 KB
  int* row_start = (int*)(ws + off); off += (size_t)NN * 4;
  int* cursor    = (int*)(ws + off); off += (size_t)NN * 4;
  int* partial   = (int*)(ws + off); off += 256;
  int* s32  = (int*)(ws + off); off += (size_t)EE * 4;          // 3.2 MB
  int* d32  = (int*)(ws + off); off += (size_t)EE * 4;          // 3.2 MB
  int* csr_src = (int*)(ws + off); off += (size_t)EE * 4;       // 3.2 MB

  hipMemsetAsync(counts, 0, (size_t)NN * 4, stream);

  k_prep<<<1024, 256, 0, stream>>>((const unsigned*)src_raw, (const unsigned*)dst_raw,
                                   s32, d32, counts, W, WbT);

  k_gemm<<<(NN + 63) / 64, 512, 0, stream>>>(h, WbT, attn_w, z, el, er);

  const int nscan = (NN + 1023) / 1024;   // 49
  k_scan1<<<nscan, 1024, 0, stream>>>(counts, row_start, partial);
  k_scan2<<<1, 64, 0, stream>>>(partial, nscan);
  k_scan3<<<(NN + 255) / 256, 256, 0, stream>>>(row_start, partial, cursor);

  k_scatter<<<1024, 256, 0, stream>>>(s32, d32, cursor, csr_src);

  k_agg<<<AGG_WAVES / 4, 256, 0, stream>>>(z, el, er, row_start, csr_src, out);
}

// Round 6
// 205.992 us; speedup vs baseline: 2.6247x; 1.0199x over previous
//
#include <hip/hip_runtime.h>
#include <math.h>

#define NN 50000
#define EE 800000
#define INDIM 256
#define DD 32
#define HH 8
#define CC 256   // H*D
#define NEG 0.01f
#define NSCAN 49  // ceil(NN/1024)

typedef __attribute__((ext_vector_type(8))) short bf16x8;
typedef __attribute__((ext_vector_type(4))) float f32x4;

__device__ __forceinline__ unsigned short f32_to_bf16_rne(float f) {
  unsigned u = __float_as_uint(f);
  u += 0x7fffu + ((u >> 16) & 1u);
  return (unsigned short)(u >> 16);
}
__device__ __forceinline__ float bf16_to_f32(unsigned short b) {
  return __uint_as_float((unsigned)b << 16);
}

// ---------- fused: dtype-detect + convert + histogram + W->bf16 ----------
__global__ __launch_bounds__(256) void k_prep(const unsigned* __restrict__ sraw,
                                              const unsigned* __restrict__ draw,
                                              int* __restrict__ s32, int* __restrict__ d32,
                                              int* __restrict__ counts,
                                              const float* __restrict__ W,
                                              unsigned short* __restrict__ WbT) {
  __shared__ int sflag;
  if (threadIdx.x == 0) sflag = 0;
  __syncthreads();
  const int gt = blockIdx.x * 256 + threadIdx.x;
  unsigned v = 0;
#pragma unroll
  for (int i = 0; i < 4; ++i) {
    int e = (gt * 4 + i) % (EE / 2);
    v |= sraw[2 * e + 1] | draw[2 * e + 1];
  }
  if (v) atomicOr(&sflag, 1);
  __syncthreads();
  const int is32 = sflag;   // 1 => int32 indices

  const int stride = gridDim.x * blockDim.x;
  for (int e = gt; e < EE; e += stride) {
    int sv, dv;
    if (is32) {
      sv = ((const int*)sraw)[e];
      dv = ((const int*)draw)[e];
    } else {
      sv = (int)((const long long*)sraw)[e];
      dv = (int)((const long long*)draw)[e];
    }
    s32[e] = sv;
    d32[e] = dv;
    atomicAdd(&counts[dv], 1);
  }

  // W -> WbT[n][k] = W[h][k][d], n=h*32+d (B^T layout)
  if (gt < INDIM * CC) {
    int n = gt >> 8, k = gt & 255;
    int hh = n >> 5, d = n & 31;
    WbT[gt] = f32_to_bf16_rne(W[(size_t)hh * 8192 + k * 32 + d]);
  }
}

// ---------- z = h @ W via bf16 MFMA (swapped operands); el/er fused ----------
__global__ __launch_bounds__(512) void k_gemm(const float* __restrict__ h,
                                              const unsigned short* __restrict__ WbT,
                                              const float* __restrict__ attn_w,
                                              unsigned short* __restrict__ z,
                                              float* __restrict__ el,
                                              float* __restrict__ er) {
  __shared__ short sA[64 * 256];   // 32 KB, [64 nodes][256 k], chunk-swizzled
  const int t = threadIdx.x;
  const int l = t & 63;
  const int w = t >> 6;            // wave index == head
  const int row0 = blockIdx.x * 64;

#pragma unroll
  for (int i = 0; i < 4; ++i) {
    int q = i * 512 + t;
    int row = q >> 5, c = q & 31;
    int grow = row0 + row; if (grow >= NN) grow = NN - 1;
    const float* src = &h[(size_t)grow * 256 + c * 8];
    float4 f0 = *reinterpret_cast<const float4*>(src);
    float4 f1 = *reinterpret_cast<const float4*>(src + 4);
    bf16x8 vv;
    vv[0] = (short)f32_to_bf16_rne(f0.x); vv[1] = (short)f32_to_bf16_rne(f0.y);
    vv[2] = (short)f32_to_bf16_rne(f0.z); vv[3] = (short)f32_to_bf16_rne(f0.w);
    vv[4] = (short)f32_to_bf16_rne(f1.x); vv[5] = (short)f32_to_bf16_rne(f1.y);
    vv[6] = (short)f32_to_bf16_rne(f1.z); vv[7] = (short)f32_to_bf16_rne(f1.w);
    int sc = c ^ (row & 7);
    *reinterpret_cast<bf16x8*>(&sA[row * 256 + sc * 8]) = vv;
  }

  bf16x8 bf[2][8];
  {
    const int n = w * 32 + (l & 15);
    const int kb = (l >> 4) * 8;
#pragma unroll
    for (int c = 0; c < 2; ++c)
#pragma unroll
      for (int kk = 0; kk < 8; ++kk)
        bf[c][kk] = *reinterpret_cast<const bf16x8*>(
            &WbT[(size_t)(n + c * 16) * 256 + kk * 32 + kb]);
  }

  f32x4 acc[4][2];
#pragma unroll
  for (int m = 0; m < 4; ++m)
#pragma unroll
    for (int c = 0; c < 2; ++c) acc[m][c] = (f32x4){0.f, 0.f, 0.f, 0.f};

  __syncthreads();

#pragma unroll
  for (int kk = 0; kk < 8; ++kk) {
    bf16x8 af[4];
#pragma unroll
    for (int m = 0; m < 4; ++m) {
      int row = m * 16 + (l & 15);
      int chunk = kk * 4 + (l >> 4);
      int sc = chunk ^ (row & 7);
      af[m] = *reinterpret_cast<const bf16x8*>(&sA[row * 256 + sc * 8]);
    }
#pragma unroll
    for (int m = 0; m < 4; ++m)
#pragma unroll
      for (int c = 0; c < 2; ++c)
        acc[m][c] = __builtin_amdgcn_mfma_f32_16x16x32_bf16(bf[c][kk], af[m], acc[m][c], 0, 0, 0);
  }

  // acc[m][c][r]: node = row0+m*16+(l&15), feat = w*32 + c*16 + (l>>4)*4 + r
#pragma unroll
  for (int m = 0; m < 4; ++m) {
    int node = row0 + m * 16 + (l & 15);
    if (node < NN) {
#pragma unroll
      for (int c = 0; c < 2; ++c) {
        ushort4 pk;
        pk.x = f32_to_bf16_rne(acc[m][c][0]);
        pk.y = f32_to_bf16_rne(acc[m][c][1]);
        pk.z = f32_to_bf16_rne(acc[m][c][2]);
        pk.w = f32_to_bf16_rne(acc[m][c][3]);
        *reinterpret_cast<ushort4*>(
            &z[(size_t)node * CC + w * 32 + c * 16 + ((l >> 4) << 2)]) = pk;
      }
    }
  }

  float alc[2][4], arc[2][4];
#pragma unroll
  for (int c = 0; c < 2; ++c)
#pragma unroll
    for (int r = 0; r < 4; ++r) {
      int d = c * 16 + ((l >> 4) << 2) + r;
      alc[c][r] = attn_w[w * 64 + d];
      arc[c][r] = attn_w[w * 64 + 32 + d];
    }
#pragma unroll
  for (int m = 0; m < 4; ++m) {
    float pl = 0.f, pr = 0.f;
#pragma unroll
    for (int c = 0; c < 2; ++c)
#pragma unroll
      for (int r = 0; r < 4; ++r) {
        pl += acc[m][c][r] * alc[c][r];
        pr += acc[m][c][r] * arc[c][r];
      }
    pl += __shfl_xor(pl, 16); pl += __shfl_xor(pl, 32);
    pr += __shfl_xor(pr, 16); pr += __shfl_xor(pr, 32);
    if ((l >> 4) == 0) {
      int node = row0 + m * 16 + l;
      if (node < NN) {
        el[(size_t)node * HH + w] = pl;
        er[(size_t)node * HH + w] = pr;
      }
    }
  }
}

// ---------- scan: per-1024-chunk exclusive scan + raw block totals ----------
__global__ __launch_bounds__(1024) void k_scan(const int* __restrict__ counts,
                                               int* __restrict__ row_start,
                                               int* __restrict__ partial) {
  __shared__ int s[1024];
  const int tid = threadIdx.x;
  const int i = blockIdx.x * 1024 + tid;
  int v = (i < NN) ? counts[i] : 0;
  s[tid] = v;
  __syncthreads();
  for (int off = 1; off < 1024; off <<= 1) {
    int tv = (tid >= off) ? s[tid - off] : 0;
    __syncthreads();
    s[tid] += tv;
    __syncthreads();
  }
  if (i < NN) row_start[i] = s[tid] - v;           // exclusive within chunk
  if (tid == 1023) partial[blockIdx.x] = s[1023];  // raw chunk total
}

// helper: wave-0 computes exclusive prefix of NSCAN partials into sbase[]
__device__ __forceinline__ void block_base_scan(const int* __restrict__ partial,
                                                int* __restrict__ sbase) {
  if (threadIdx.x < 64) {
    int l = threadIdx.x;
    int x = (l < NSCAN) ? partial[l] : 0;
    int orig = x;
#pragma unroll
    for (int off = 1; off < 64; off <<= 1) {
      int y = __shfl_up(x, off);
      if (l >= off) x += y;
    }
    sbase[l] = x - orig;
  }
  __syncthreads();
}

__global__ __launch_bounds__(256) void k_scatter(const int* __restrict__ s32,
                                                 const int* __restrict__ d32,
                                                 const int* __restrict__ row_start,
                                                 const int* __restrict__ partial,
                                                 int* __restrict__ cursor,
                                                 int* __restrict__ csr_src) {
  __shared__ int sbase[64];
  block_base_scan(partial, sbase);
  int stride = gridDim.x * blockDim.x;
  for (int e = blockIdx.x * blockDim.x + threadIdx.x; e < EE; e += stride) {
    int dn = d32[e];
    int pos = row_start[dn] + sbase[dn >> 10] + atomicAdd(&cursor[dn], 1);
    csr_src[pos] = s32[e];
  }
}

// ---------- per-node softmax-aggregate: 64-edge LDS batches ----------
#define AGG_WAVES 8192
__global__ __launch_bounds__(256) void k_agg(const unsigned short* __restrict__ z,
                                             const float* __restrict__ el,
                                             const float* __restrict__ er,
                                             const int* __restrict__ row_start,
                                             const int* __restrict__ partial,
                                             const int* __restrict__ csr_src,
                                             float* __restrict__ out) {
  __shared__ int sbase[64];
  __shared__ float swgt[4][64 * 8];   // [wave][edge][head]
  __shared__ int ssrc[4][64];
  block_base_scan(partial, sbase);

  const int wid = threadIdx.x >> 6;
  const int gw = blockIdx.x * 4 + wid;
  const int l = threadIdx.x & 63;
  const int head = l >> 3;
  float* __restrict__ wgt_l = swgt[wid];
  int* __restrict__ src_l = ssrc[wid];

  for (int n = gw; n < NN; n += AGG_WAVES) {
    const int beg = row_start[n] + sbase[n >> 10];
    const int end = (n == NN - 1) ? EE : (row_start[n + 1] + sbase[(n + 1) >> 10]);
    float4 er0 = *reinterpret_cast<const float4*>(&er[(size_t)n * 8]);
    float4 er1 = *reinterpret_cast<const float4*>(&er[(size_t)n * 8 + 4]);

    float den = 0.f;
    float a0 = 0.f, a1 = 0.f, a2 = 0.f, a3 = 0.f;

    for (int base = beg; base < end; base += 64) {
      int cnt = end - base; if (cnt > 64) cnt = 64;
      int p = base + l;
      int s = csr_src[(p < end) ? p : (end - 1)];
      float4 e0 = *reinterpret_cast<const float4*>(&el[(size_t)s * 8]);
      float4 e1 = *reinterpret_cast<const float4*>(&el[(size_t)s * 8 + 4]);
      float4 w0, w1;
      {
        float v;
        v = e0.x + er0.x; v = (v > 0.f) ? v : v * NEG; w0.x = __expf(v);
        v = e0.y + er0.y; v = (v > 0.f) ? v : v * NEG; w0.y = __expf(v);
        v = e0.z + er0.z; v = (v > 0.f) ? v : v * NEG; w0.z = __expf(v);
        v = e0.w + er0.w; v = (v > 0.f) ? v : v * NEG; w0.w = __expf(v);
        v = e1.x + er1.x; v = (v > 0.f) ? v : v * NEG; w1.x = __expf(v);
        v = e1.y + er1.y; v = (v > 0.f) ? v : v * NEG; w1.y = __expf(v);
        v = e1.z + er1.z; v = (v > 0.f) ? v : v * NEG; w1.z = __expf(v);
        v = e1.w + er1.w; v = (v > 0.f) ? v : v * NEG; w1.w = __expf(v);
      }
      *reinterpret_cast<float4*>(&wgt_l[l * 8]) = w0;
      *reinterpret_cast<float4*>(&wgt_l[l * 8 + 4]) = w1;
      src_l[l] = s;
#pragma unroll 8
      for (int jj = 0; jj < cnt; ++jj) {
        int s_jj = src_l[jj];
        float wgt = wgt_l[jj * 8 + head];
        den += wgt;
        ushort4 zv = *reinterpret_cast<const ushort4*>(&z[(size_t)s_jj * CC + 4 * l]);
        a0 += wgt * bf16_to_f32(zv.x);
        a1 += wgt * bf16_to_f32(zv.y);
        a2 += wgt * bf16_to_f32(zv.z);
        a3 += wgt * bf16_to_f32(zv.w);
      }
    }
    const float rd = (end > beg) ? (1.f / den) : 0.f;
    float4 o;
    o.x = a0 * rd; o.y = a1 * rd; o.z = a2 * rd; o.w = a3 * rd;
    *reinterpret_cast<float4*>(&out[(size_t)n * CC + 4 * l]) = o;
  }
}

extern "C" void kernel_launch(void* const* d_in, const int* in_sizes, int n_in,
                              void* d_out, int out_size, void* d_ws, size_t ws_size,
                              hipStream_t stream) {
  const float* h      = (const float*)d_in[0];
  const float* W      = (const float*)d_in[1];
  const float* attn_w = (const float*)d_in[2];
  const void*  src_raw = d_in[3];
  const void*  dst_raw = d_in[4];
  float* out = (float*)d_out;

  char* ws = (char*)d_ws;
  size_t off = 0;
  unsigned short* z   = (unsigned short*)(ws + off); off += (size_t)NN * CC * 2;     // 25.6 MB
  unsigned short* WbT = (unsigned short*)(ws + off); off += (size_t)INDIM * CC * 2;  // 128 KB
  float* el = (float*)(ws + off); off += (size_t)NN * HH * 4;   // 1.6 MB
  float* er = (float*)(ws + off); off += (size_t)NN * HH * 4;   // 1.6 MB
  int* counts    = (int*)(ws + off); off += (size_t)NN * 4;     // 200 KB \ zeroed in
  int* cursor    = (int*)(ws + off); off += (size_t)NN * 4;     // 200 KB / one memset
  int* row_start = (int*)(ws + off); off += (size_t)NN * 4;
  int* partial   = (int*)(ws + off); off += 256;
  int* s32  = (int*)(ws + off); off += (size_t)EE * 4;          // 3.2 MB
  int* d32  = (int*)(ws + off); off += (size_t)EE * 4;          // 3.2 MB
  int* csr_src = (int*)(ws + off); off += (size_t)EE * 4;       // 3.2 MB

  hipMemsetAsync(counts, 0, (size_t)NN * 8, stream);   // counts + cursor

  k_prep<<<1024, 256, 0, stream>>>((const unsigned*)src_raw, (const unsigned*)dst_raw,
                                   s32, d32, counts, W, WbT);

  k_gemm<<<(NN + 63) / 64, 512, 0, stream>>>(h, WbT, attn_w, z, el, er);

  k_scan<<<NSCAN, 1024, 0, stream>>>(counts, row_start, partial);

  k_scatter<<<2048, 256, 0, stream>>>(s32, d32, row_start, partial, cursor, csr_src);

  k_agg<<<AGG_WAVES / 4, 256, 0, stream>>>(z, el, er, row_start, partial, csr_src, out);
}

// Round 7
// 167.899 us; speedup vs baseline: 3.2201x; 1.2269x over previous
//
#include <hip/hip_runtime.h>
#include <math.h>

#define NN 50000
#define EE 800000
#define INDIM 256
#define DD 32
#define HH 8
#define CC 256   // H*D
#define NEG 0.01f
#define NSCAN 49  // ceil(NN/1024)

typedef __attribute__((ext_vector_type(8))) short bf16x8;
typedef __attribute__((ext_vector_type(4))) float f32x4;

__device__ __forceinline__ unsigned short f32_to_bf16_rne(float f) {
  unsigned u = __float_as_uint(f);
  u += 0x7fffu + ((u >> 16) & 1u);
  return (unsigned short)(u >> 16);
}
__device__ __forceinline__ float bf16_to_f32(unsigned short b) {
  return __uint_as_float((unsigned)b << 16);
}

// ---------- fused: dtype-detect + convert + histogram(+slot) + W->bf16 ----------
// slot[e] = this edge's arrival index within its dst node (from the histogram
// atomic's return value) -> scatter needs no second atomic pass.
__global__ __launch_bounds__(256) void k_prep(const unsigned* __restrict__ sraw,
                                              const unsigned* __restrict__ draw,
                                              int* __restrict__ s32, int* __restrict__ d32,
                                              unsigned short* __restrict__ slot,
                                              int* __restrict__ counts,
                                              const float* __restrict__ W,
                                              unsigned short* __restrict__ WbT) {
  __shared__ int sflag;
  if (threadIdx.x == 0) sflag = 0;
  __syncthreads();
  const int gt = blockIdx.x * 256 + threadIdx.x;
  unsigned v = 0;
#pragma unroll
  for (int i = 0; i < 4; ++i) {
    int e = (gt * 4 + i) % (EE / 2);
    v |= sraw[2 * e + 1] | draw[2 * e + 1];
  }
  if (v) atomicOr(&sflag, 1);
  __syncthreads();
  const int is32 = sflag;   // 1 => int32 indices

  const int stride = gridDim.x * blockDim.x;
  for (int e = gt; e < EE; e += stride) {
    int sv, dv;
    if (is32) {
      sv = ((const int*)sraw)[e];
      dv = ((const int*)draw)[e];
    } else {
      sv = (int)((const long long*)sraw)[e];
      dv = (int)((const long long*)draw)[e];
    }
    s32[e] = sv;
    d32[e] = dv;
    slot[e] = (unsigned short)atomicAdd(&counts[dv], 1);
  }

  // W -> WbT[n][k] = W[h][k][d], n=h*32+d (B^T layout)
  if (gt < INDIM * CC) {
    int n = gt >> 8, k = gt & 255;
    int hh = n >> 5, d = n & 31;
    WbT[gt] = f32_to_bf16_rne(W[(size_t)hh * 8192 + k * 32 + d]);
  }
}

// ---------- z = h @ W via bf16 MFMA (swapped operands); el/er fused ----------
__global__ __launch_bounds__(512) void k_gemm(const float* __restrict__ h,
                                              const unsigned short* __restrict__ WbT,
                                              const float* __restrict__ attn_w,
                                              unsigned short* __restrict__ z,
                                              float* __restrict__ el,
                                              float* __restrict__ er) {
  __shared__ short sA[64 * 256];   // 32 KB, [64 nodes][256 k], chunk-swizzled
  const int t = threadIdx.x;
  const int l = t & 63;
  const int w = t >> 6;            // wave index == head
  const int row0 = blockIdx.x * 64;

#pragma unroll
  for (int i = 0; i < 4; ++i) {
    int q = i * 512 + t;
    int row = q >> 5, c = q & 31;
    int grow = row0 + row; if (grow >= NN) grow = NN - 1;
    const float* src = &h[(size_t)grow * 256 + c * 8];
    float4 f0 = *reinterpret_cast<const float4*>(src);
    float4 f1 = *reinterpret_cast<const float4*>(src + 4);
    bf16x8 vv;
    vv[0] = (short)f32_to_bf16_rne(f0.x); vv[1] = (short)f32_to_bf16_rne(f0.y);
    vv[2] = (short)f32_to_bf16_rne(f0.z); vv[3] = (short)f32_to_bf16_rne(f0.w);
    vv[4] = (short)f32_to_bf16_rne(f1.x); vv[5] = (short)f32_to_bf16_rne(f1.y);
    vv[6] = (short)f32_to_bf16_rne(f1.z); vv[7] = (short)f32_to_bf16_rne(f1.w);
    int sc = c ^ (row & 7);
    *reinterpret_cast<bf16x8*>(&sA[row * 256 + sc * 8]) = vv;
  }

  bf16x8 bf[2][8];
  {
    const int n = w * 32 + (l & 15);
    const int kb = (l >> 4) * 8;
#pragma unroll
    for (int c = 0; c < 2; ++c)
#pragma unroll
      for (int kk = 0; kk < 8; ++kk)
        bf[c][kk] = *reinterpret_cast<const bf16x8*>(
            &WbT[(size_t)(n + c * 16) * 256 + kk * 32 + kb]);
  }

  f32x4 acc[4][2];
#pragma unroll
  for (int m = 0; m < 4; ++m)
#pragma unroll
    for (int c = 0; c < 2; ++c) acc[m][c] = (f32x4){0.f, 0.f, 0.f, 0.f};

  __syncthreads();

#pragma unroll
  for (int kk = 0; kk < 8; ++kk) {
    bf16x8 af[4];
#pragma unroll
    for (int m = 0; m < 4; ++m) {
      int row = m * 16 + (l & 15);
      int chunk = kk * 4 + (l >> 4);
      int sc = chunk ^ (row & 7);
      af[m] = *reinterpret_cast<const bf16x8*>(&sA[row * 256 + sc * 8]);
    }
#pragma unroll
    for (int m = 0; m < 4; ++m)
#pragma unroll
      for (int c = 0; c < 2; ++c)
        acc[m][c] = __builtin_amdgcn_mfma_f32_16x16x32_bf16(bf[c][kk], af[m], acc[m][c], 0, 0, 0);
  }

  // acc[m][c][r]: node = row0+m*16+(l&15), feat = w*32 + c*16 + (l>>4)*4 + r
#pragma unroll
  for (int m = 0; m < 4; ++m) {
    int node = row0 + m * 16 + (l & 15);
    if (node < NN) {
#pragma unroll
      for (int c = 0; c < 2; ++c) {
        ushort4 pk;
        pk.x = f32_to_bf16_rne(acc[m][c][0]);
        pk.y = f32_to_bf16_rne(acc[m][c][1]);
        pk.z = f32_to_bf16_rne(acc[m][c][2]);
        pk.w = f32_to_bf16_rne(acc[m][c][3]);
        *reinterpret_cast<ushort4*>(
            &z[(size_t)node * CC + w * 32 + c * 16 + ((l >> 4) << 2)]) = pk;
      }
    }
  }

  float alc[2][4], arc[2][4];
#pragma unroll
  for (int c = 0; c < 2; ++c)
#pragma unroll
    for (int r = 0; r < 4; ++r) {
      int d = c * 16 + ((l >> 4) << 2) + r;
      alc[c][r] = attn_w[w * 64 + d];
      arc[c][r] = attn_w[w * 64 + 32 + d];
    }
#pragma unroll
  for (int m = 0; m < 4; ++m) {
    float pl = 0.f, pr = 0.f;
#pragma unroll
    for (int c = 0; c < 2; ++c)
#pragma unroll
      for (int r = 0; r < 4; ++r) {
        pl += acc[m][c][r] * alc[c][r];
        pr += acc[m][c][r] * arc[c][r];
      }
    pl += __shfl_xor(pl, 16); pl += __shfl_xor(pl, 32);
    pr += __shfl_xor(pr, 16); pr += __shfl_xor(pr, 32);
    if ((l >> 4) == 0) {
      int node = row0 + m * 16 + l;
      if (node < NN) {
        el[(size_t)node * HH + w] = pl;
        er[(size_t)node * HH + w] = pr;
      }
    }
  }
}

// ---------- scan: per-1024-chunk exclusive scan + raw block totals ----------
__global__ __launch_bounds__(1024) void k_scan(const int* __restrict__ counts,
                                               int* __restrict__ row_start,
                                               int* __restrict__ partial) {
  __shared__ int s[1024];
  const int tid = threadIdx.x;
  const int i = blockIdx.x * 1024 + tid;
  int v = (i < NN) ? counts[i] : 0;
  s[tid] = v;
  __syncthreads();
  for (int off = 1; off < 1024; off <<= 1) {
    int tv = (tid >= off) ? s[tid - off] : 0;
    __syncthreads();
    s[tid] += tv;
    __syncthreads();
  }
  if (i < NN) row_start[i] = s[tid] - v;           // exclusive within chunk
  if (tid == 1023) partial[blockIdx.x] = s[1023];  // raw chunk total
}

// helper: wave-0 computes exclusive prefix of NSCAN partials into sbase[]
__device__ __forceinline__ void block_base_scan(const int* __restrict__ partial,
                                                int* __restrict__ sbase) {
  if (threadIdx.x < 64) {
    int l = threadIdx.x;
    int x = (l < NSCAN) ? partial[l] : 0;
    int orig = x;
#pragma unroll
    for (int off = 1; off < 64; off <<= 1) {
      int y = __shfl_up(x, off);
      if (l >= off) x += y;
    }
    sbase[l] = x - orig;
  }
  __syncthreads();
}

// ---------- scatter: atomic-free (slot precomputed in k_prep) ----------
__global__ __launch_bounds__(256) void k_scatter(const int* __restrict__ s32,
                                                 const int* __restrict__ d32,
                                                 const unsigned short* __restrict__ slot,
                                                 const int* __restrict__ row_start,
                                                 const int* __restrict__ partial,
                                                 int* __restrict__ csr_src) {
  __shared__ int sbase[64];
  block_base_scan(partial, sbase);
  int stride = gridDim.x * blockDim.x;
  for (int e = blockIdx.x * blockDim.x + threadIdx.x; e < EE; e += stride) {
    int dn = d32[e];
    int pos = row_start[dn] + sbase[dn >> 10] + (int)slot[e];
    csr_src[pos] = s32[e];
  }
}

// ---------- per-node softmax-aggregate (round-4 form: known-best) ----------
#define AGG_WAVES 8192
__global__ __launch_bounds__(256) void k_agg(const unsigned short* __restrict__ z,
                                             const float* __restrict__ el,
                                             const float* __restrict__ er,
                                             const int* __restrict__ row_start,
                                             const int* __restrict__ partial,
                                             const int* __restrict__ csr_src,
                                             float* __restrict__ out) {
  __shared__ int sbase[64];
  block_base_scan(partial, sbase);

  const int gw = blockIdx.x * 4 + (threadIdx.x >> 6);
  const int l = threadIdx.x & 63;
  const int head = l >> 3;

  for (int n = gw; n < NN; n += AGG_WAVES) {
    const int beg = row_start[n] + sbase[n >> 10];
    const int end = (n == NN - 1) ? EE : (row_start[n + 1] + sbase[(n + 1) >> 10]);
    const float ern = er[(size_t)n * HH + head];

    float den = 0.f;
    float a0 = 0.f, a1 = 0.f, a2 = 0.f, a3 = 0.f;
#pragma unroll 4
    for (int p = beg; p < end; ++p) {
      int s = csr_src[p];
      float v = el[(size_t)s * HH + head] + ern;
      v = (v > 0.f) ? v : v * NEG;
      float wgt = __expf(v);
      ushort4 zv = *reinterpret_cast<const ushort4*>(&z[(size_t)s * CC + 4 * l]);
      den += wgt;
      a0 += wgt * bf16_to_f32(zv.x);
      a1 += wgt * bf16_to_f32(zv.y);
      a2 += wgt * bf16_to_f32(zv.z);
      a3 += wgt * bf16_to_f32(zv.w);
    }
    const float rd = (end > beg) ? (1.f / den) : 0.f;
    float4 o;
    o.x = a0 * rd; o.y = a1 * rd; o.z = a2 * rd; o.w = a3 * rd;
    *reinterpret_cast<float4*>(&out[(size_t)n * CC + 4 * l]) = o;
  }
}

extern "C" void kernel_launch(void* const* d_in, const int* in_sizes, int n_in,
                              void* d_out, int out_size, void* d_ws, size_t ws_size,
                              hipStream_t stream) {
  const float* h      = (const float*)d_in[0];
  const float* W      = (const float*)d_in[1];
  const float* attn_w = (const float*)d_in[2];
  const void*  src_raw = d_in[3];
  const void*  dst_raw = d_in[4];
  float* out = (float*)d_out;

  char* ws = (char*)d_ws;
  size_t off = 0;
  unsigned short* z   = (unsigned short*)(ws + off); off += (size_t)NN * CC * 2;     // 25.6 MB
  unsigned short* WbT = (unsigned short*)(ws + off); off += (size_t)INDIM * CC * 2;  // 128 KB
  float* el = (float*)(ws + off); off += (size_t)NN * HH * 4;   // 1.6 MB
  float* er = (float*)(ws + off); off += (size_t)NN * HH * 4;   // 1.6 MB
  int* counts    = (int*)(ws + off); off += (size_t)NN * 4;     // 200 KB (memset)
  int* row_start = (int*)(ws + off); off += (size_t)NN * 4;
  int* partial   = (int*)(ws + off); off += 256;
  int* s32  = (int*)(ws + off); off += (size_t)EE * 4;          // 3.2 MB
  int* d32  = (int*)(ws + off); off += (size_t)EE * 4;          // 3.2 MB
  unsigned short* slot = (unsigned short*)(ws + off); off += (size_t)EE * 2;  // 1.6 MB
  int* csr_src = (int*)(ws + off); off += (size_t)EE * 4;       // 3.2 MB

  hipMemsetAsync(counts, 0, (size_t)NN * 4, stream);

  k_prep<<<1024, 256, 0, stream>>>((const unsigned*)src_raw, (const unsigned*)dst_raw,
                                   s32, d32, slot, counts, W, WbT);

  k_gemm<<<(NN + 63) / 64, 512, 0, stream>>>(h, WbT, attn_w, z, el, er);

  k_scan<<<NSCAN, 1024, 0, stream>>>(counts, row_start, partial);

  k_scatter<<<2048, 256, 0, stream>>>(s32, d32, slot, row_start, partial, csr_src);

  k_agg<<<AGG_WAVES / 4, 256, 0, stream>>>(z, el, er, row_start, partial, csr_src, out);
}